// Round 11
// baseline (306.475 us; speedup 1.0000x reference)
//
#include <hip/hip_runtime.h>
#include <hip/hip_bf16.h>
#include <math.h>

typedef __attribute__((ext_vector_type(8))) short bf16x8;
typedef __attribute__((ext_vector_type(4))) float f32x4;

__device__ __forceinline__ float bf2f(ushort u) {
  union { unsigned u; float f; } v; v.u = ((unsigned)u) << 16; return v.f;
}
__device__ __forceinline__ ushort f2bf(float f) {
  union { float f; unsigned u; } v; v.f = f;
  unsigned r = v.u + 0x7FFFu + ((v.u >> 16) & 1u);
  return (ushort)(r >> 16);
}
#if __has_builtin(__builtin_amdgcn_exp2f)
#define EXP2F(x) __builtin_amdgcn_exp2f(x)
#else
#define EXP2F(x) exp2f(x)
#endif
__device__ __forceinline__ void gl_lds16(const ushort* g, ushort* l) {
  __builtin_amdgcn_global_load_lds(
      (const __attribute__((address_space(1))) unsigned int*)g,
      (__attribute__((address_space(3))) unsigned int*)l, 16, 0, 0);
}

// -------- workspace layout (ushort elements, after 256B header) --------
static const long XB   = 0;              // x bf16 (4096x2048); reused as attn-out
static const long WQB  = 8388608;        // wq (2048x2048)
static const long WKB  = 12582912;       // wk (512x2048)
static const long WVB  = 13631488;       // wv (512x2048)
static const long WOB  = 14680064;       // wo (2048x2048)
static const long COSB = 18874368;       // cos (2*2048*64)
static const long SINB = 19136512;       // sin
static const long QB   = 19398656;       // q (4096x2048)
static const long KB   = 27787264;       // k (4096x512)
static const long VTB  = 29884416;       // v^T (512x4096)

// ---------------- fused cast of all 7 inputs + dtype self-detection --------
__global__ void cast_all(const void* __restrict__ s0, const void* __restrict__ s1,
                         const void* __restrict__ s2, const void* __restrict__ s3,
                         const void* __restrict__ s4, const void* __restrict__ s5,
                         const void* __restrict__ s6,
                         ushort* __restrict__ d0, ushort* __restrict__ d1,
                         ushort* __restrict__ d2, ushort* __restrict__ d3,
                         ushort* __restrict__ d4, ushort* __restrict__ d5,
                         ushort* __restrict__ d6, int* __restrict__ flag) {
  __shared__ int cnt;
  if (threadIdx.x == 0) cnt = 0;
  __syncthreads();
  const ushort* xu = (const ushort*)s0;
  int local = 0;
  for (int j = 0; j < 32; j++) {
    ushort u = xu[threadIdx.x + j * 256];
    int e = (u >> 7) & 0xFF;
    if (e >= 100 && e <= 142) local++;
  }
  atomicAdd(&cnt, local);
  __syncthreads();
  const bool isbf = (cnt >= 6554);
  if (threadIdx.x == 0 && blockIdx.x == 0) *flag = isbf ? 1 : 0;
  if (isbf) return;
  const long N = 2424832;
  for (long i = (long)blockIdx.x * blockDim.x + threadIdx.x; i < N;
       i += (long)gridDim.x * blockDim.x) {
    const float4* s; ushort* d; long off;
    if      (i < 1048576) { s = (const float4*)s0; d = d0; off = i; }
    else if (i < 1572864) { s = (const float4*)s1; d = d1; off = i - 1048576; }
    else if (i < 1703936) { s = (const float4*)s2; d = d2; off = i - 1572864; }
    else if (i < 1835008) { s = (const float4*)s3; d = d3; off = i - 1703936; }
    else if (i < 2359296) { s = (const float4*)s4; d = d4; off = i - 1835008; }
    else if (i < 2392064) { s = (const float4*)s5; d = d5; off = i - 2359296; }
    else                  { s = (const float4*)s6; d = d6; off = i - 2392064; }
    float4 a = s[2 * off], b = s[2 * off + 1];
    uint4 o;
    o.x = (unsigned)f2bf(a.x) | ((unsigned)f2bf(a.y) << 16);
    o.y = (unsigned)f2bf(a.z) | ((unsigned)f2bf(a.w) << 16);
    o.z = (unsigned)f2bf(b.x) | ((unsigned)f2bf(b.y) << 16);
    o.w = (unsigned)f2bf(b.z) | ((unsigned)f2bf(b.w) << 16);
    ((uint4*)d)[off] = o;
  }
}

// ---------------- bf16 GEMM body: C tile = A[M,K] * W[N,K]^T ----------------
// Round-3 verified structure (BK=32, 2 barriers/K-step, global_load_lds) —
// DO NOT PERTURB the schedule (R4/R5 ring-3, R6 dbuf, R8 BK=64 all regressed).
// Round-11 adds the attn-proven T2 chunk-swizzle (rule #21, both sides):
// global source chunk c -> c ^ ((row>>1)&3) with linear LDS dest; reads use
// quad -> quad ^ ((l15>>1)&3) (wm,wn in {0,64} and t*16 are 0 mod 4 after
// >>1, so one per-thread constant; involution exact). Before: [row][32]
// panels at 64B stride = 8-way read conflict (6.29M cyc/dispatch = ~15% of
// gemm_qkv). After: 2 lanes/bank-group = free (m136).
__device__ __forceinline__ void gemm_body(
    const ushort* __restrict__ A, const ushort* __restrict__ W, void* __restrict__ C,
    int N, int K, int bm, int bn, bool ofp32, ushort* As, ushort* Ws) {
  const int tid = threadIdx.x;
  const int wave = tid >> 6, lane = tid & 63;
  const int quad = lane >> 4, l15 = lane & 15;
  const int wm = (wave >> 1) * 64, wn = (wave & 1) * 64;
  const int srow = tid >> 2;
  // swizzled source chunk: LDS chunk (tid&3) of row srow receives global
  // chunk (tid&3) ^ ((srow>>1)&3); row srow+64 has the same XOR (64>>1=32=0 mod 4)
  const int sk = (((tid & 3) ^ ((srow >> 1) & 3)) * 8);
  const ushort* Ap = A + (size_t)(bm + srow) * K + sk;
  const ushort* Wp = W + (size_t)(bn + srow) * K + sk;
  ushort* AsW = As + wave * 512;
  ushort* WsW = Ws + wave * 512;
  // read-side swizzle constant: row = wm/wn + t*16 + l15 -> XOR = (l15>>1)&3
  const int rq8 = (quad ^ ((l15 >> 1) & 3)) * 8;
  f32x4 acc[4][4] = {};
  for (int k0 = 0; k0 < K; k0 += 32) {
    __syncthreads();
    gl_lds16(Ap + k0, AsW);
    gl_lds16(Ap + (size_t)64 * K + k0, AsW + 2048);
    gl_lds16(Wp + k0, WsW);
    gl_lds16(Wp + (size_t)64 * K + k0, WsW + 2048);
    __syncthreads();
    bf16x8 af[4], wf[4];
#pragma unroll
    for (int t = 0; t < 4; t++)
      af[t] = *(const bf16x8*)&As[(wm + t * 16 + l15) * 32 + rq8];
#pragma unroll
    for (int t = 0; t < 4; t++)
      wf[t] = *(const bf16x8*)&Ws[(wn + t * 16 + l15) * 32 + rq8];
#pragma unroll
    for (int mt = 0; mt < 4; mt++)
#pragma unroll
      for (int nt = 0; nt < 4; nt++)
        acc[mt][nt] = __builtin_amdgcn_mfma_f32_16x16x32_bf16(af[mt], wf[nt], acc[mt][nt], 0, 0, 0);
  }
  if (!ofp32) {
    ushort* Cb = (ushort*)C;
#pragma unroll
    for (int mt = 0; mt < 4; mt++)
#pragma unroll
      for (int nt = 0; nt < 4; nt++)
#pragma unroll
        for (int r = 0; r < 4; r++) {
          int row = bm + wm + mt * 16 + quad * 4 + r;
          int col = bn + wn + nt * 16 + l15;
          Cb[(size_t)row * N + col] = f2bf(acc[mt][nt][r]);
        }
  } else {
    float* Cf = (float*)C;
#pragma unroll
    for (int mt = 0; mt < 4; mt++)
#pragma unroll
      for (int nt = 0; nt < 4; nt++)
#pragma unroll
        for (int r = 0; r < 4; r++) {
          int row = bm + wm + mt * 16 + quad * 4 + r;
          int col = bn + wn + nt * 16 + l15;
          Cf[(size_t)row * N + col] = acc[mt][nt][r];
        }
  }
}

// fused Q/K/V^T projection: 1D grid 768. [0,512) Q; [512,640) K; [640,768) V^T.
__global__ __launch_bounds__(256) void gemm_qkv(
    const ushort* __restrict__ xws, const ushort* __restrict__ xorig,
    const ushort* __restrict__ wqws, const ushort* __restrict__ wqorig,
    const ushort* __restrict__ wkws, const ushort* __restrict__ wkorig,
    const ushort* __restrict__ wvws, const ushort* __restrict__ wvorig,
    ushort* __restrict__ qout, ushort* __restrict__ kout, ushort* __restrict__ vtout,
    const int* __restrict__ flag) {
  __shared__ __align__(16) ushort As[128 * 32];
  __shared__ __align__(16) ushort Ws[128 * 32];
  const bool bf = (*flag != 0);
  const ushort* x = bf ? xorig : xws;
  const int id = blockIdx.x;
  if (id < 512) {
    gemm_body(x, bf ? wqorig : wqws, qout, 2048, 2048, (id >> 4) * 128, (id & 15) * 128, false, As, Ws);
  } else if (id < 640) {
    int t = id - 512;
    gemm_body(x, bf ? wkorig : wkws, kout, 512, 2048, (t >> 2) * 128, (t & 3) * 128, false, As, Ws);
  } else {
    int t = id - 640;
    gemm_body(bf ? wvorig : wvws, x, vtout, 4096, 2048, (t & 3) * 128, (t >> 2) * 128, false, As, Ws);
  }
}

__global__ __launch_bounds__(256) void gemm_bt(
    const ushort* __restrict__ Aws, const ushort* __restrict__ Aorig,
    const ushort* __restrict__ Wws, const ushort* __restrict__ Worig,
    void* __restrict__ C, int N, int K, const int* __restrict__ flag, int outMode) {
  __shared__ __align__(16) ushort As[128 * 32];
  __shared__ __align__(16) ushort Ws[128 * 32];
  const bool bf = (*flag != 0);
  const ushort* A = (bf && Aorig) ? Aorig : Aws;
  const ushort* W = (bf && Worig) ? Worig : Wws;
  bool ofp32 = (outMode == 1) && !bf;
  gemm_body(A, W, C, N, K, blockIdx.y * 128, blockIdx.x * 128, ofp32, As, Ws);
}

// ---------------- RoPE (K only; Q rope fused into attn prologue) -----------
__global__ void rope_kernel(ushort* __restrict__ Kb,
                            const ushort* __restrict__ cws, const ushort* __restrict__ corig,
                            const ushort* __restrict__ sws, const ushort* __restrict__ sorig,
                            const int* __restrict__ flag) {
  const ushort* cb = (*flag) ? corig : cws;
  const ushort* sb = (*flag) ? sorig : sws;
  int j = blockIdx.x * 256 + threadIdx.x;   // 0..131071
  long row = j >> 5; int rest = j & 31; int c8 = (rest & 3) * 8;
  ushort* base = Kb + row * 512 + (rest >> 2) * 64 + c8;
  uint4 lo4 = *(const uint4*)base;
  uint4 hi4 = *(const uint4*)(base + 32);
  uint4 cl4 = *(const uint4*)(cb + row * 64 + c8);
  uint4 ch4 = *(const uint4*)(cb + row * 64 + c8 + 32);
  uint4 sl4 = *(const uint4*)(sb + row * 64 + c8);
  uint4 sh4 = *(const uint4*)(sb + row * 64 + c8 + 32);
  const ushort* lo = (const ushort*)&lo4; const ushort* hi = (const ushort*)&hi4;
  const ushort* cl = (const ushort*)&cl4; const ushort* ch = (const ushort*)&ch4;
  const ushort* sl = (const ushort*)&sl4; const ushort* sh = (const ushort*)&sh4;
  uint4 olo, ohi;
  ushort* po = (ushort*)&olo; ushort* ph = (ushort*)&ohi;
#pragma unroll
  for (int k = 0; k < 8; k++) {
    float l = bf2f(lo[k]), h = bf2f(hi[k]);
    po[k] = f2bf(l * bf2f(cl[k]) - h * bf2f(sl[k]));
    ph[k] = f2bf(h * bf2f(ch[k]) + l * bf2f(sh[k]));
  }
  *(uint4*)base = olo;
  *(uint4*)(base + 32) = ohi;
}

// ---------------- causal GQA flash attention ----------------
// Round-10 winner: swapped QK^T, fused Q-RoPE, K/V dbuf prefetch, LPT,
// T2 chunk-swizzle on K/V LDS (conflicts 11.89M -> ~0, +7us), softmax diet.
__global__ __launch_bounds__(512, 4) void attn_kernel(
    const ushort* __restrict__ Qb, const ushort* __restrict__ Kb,
    const ushort* __restrict__ Vt,
    const ushort* __restrict__ cws, const ushort* __restrict__ corig,
    const ushort* __restrict__ sws, const ushort* __restrict__ sorig,
    ushort* __restrict__ Ob, const int* __restrict__ flag) {
  __shared__ __align__(16) ushort Ks[2][4096];  // [buf][kc][s][32], chunk-swizzled
  __shared__ __align__(16) ushort Vs[2][4096];  // [buf][sc][d][32], chunk-swizzled
  __shared__ __align__(16) ushort Ps[128 * 72]; // [q][s], wave-private rows
  const int tid = threadIdx.x;
  const int wave = tid >> 6, lane = tid & 63;
  const int quad = lane >> 4, l15 = lane & 15;
  const int id = blockIdx.x;
  const int kvh = id & 7;                  // XCD-pinned KV head
  const int b = (id >> 3) & 1;
  const int hsub = (id >> 4) & 3;
  const int h = kvh * 4 + hsub;
  const int t = 15 - (id >> 6);            // LPT: heavy tiles dispatch first
  const size_t brow = (size_t)b * 2048;
  const ushort* Kg = Kb + brow * 512 + (size_t)kvh * 64;
  const ushort* Vg = Vt + (size_t)(kvh * 64) * 4096 + brow;

  // staging decode: each of the 8 waves stages 1 of 8 1KB segments of K and V.
  const int prow = wave * 16 + (lane >> 2);       // panel-row
  const int chunk = (((lane & 3) ^ ((prow >> 1) & 3)) * 8);
  const int k_s = prow & 63, k_kc = prow >> 6;
  const int v_d = prow & 63, v_sc = prow >> 6;
  const int ldsW = wave * 512;

  const int q0 = t * 128;
  const int wrow0 = q0 + wave * 16;
  const int blockNt = 2 * t + 2;
  const int myLast = wrow0 >> 6;           // last KV tile this wave computes

  // prologue: stage tile 0 into buffer 0
  gl_lds16(Kg + (size_t)k_s * 512 + k_kc * 32 + chunk, &Ks[0][ldsW]);
  gl_lds16(Vg + (size_t)v_d * 4096 + v_sc * 32 + chunk, &Vs[0][ldsW]);

  // ---- Q load + in-register RoPE (+ attn scale in log2 units) ----
  const ushort* cb = (*flag) ? corig : cws;
  const ushort* sp = (*flag) ? sorig : sws;
  const size_t qrow_g = brow + wrow0 + l15;
  bf16x8 qlo = *(const bf16x8*)&Qb[qrow_g * 2048 + h * 64 + quad * 8];
  bf16x8 qhi = *(const bf16x8*)&Qb[qrow_g * 2048 + h * 64 + 32 + quad * 8];
  bf16x8 cl = *(const bf16x8*)&cb[qrow_g * 64 + quad * 8];
  bf16x8 ch = *(const bf16x8*)&cb[qrow_g * 64 + 32 + quad * 8];
  bf16x8 sl = *(const bf16x8*)&sp[qrow_g * 64 + quad * 8];
  bf16x8 sh = *(const bf16x8*)&sp[qrow_g * 64 + 32 + quad * 8];
  bf16x8 qf[2];
  const float scl = 0.18033688011112f;     // 0.125 * log2(e)
#pragma unroll
  for (int j = 0; j < 8; j++) {
    float l = bf2f((ushort)qlo[j]), hg = bf2f((ushort)qhi[j]);
    qf[0][j] = (short)f2bf((l * bf2f((ushort)cl[j]) - hg * bf2f((ushort)sl[j])) * scl);
    qf[1][j] = (short)f2bf((hg * bf2f((ushort)ch[j]) + l * bf2f((ushort)sh[j])) * scl);
  }

  // read-side swizzle constant: row = ct*16 + l15 -> ((row>>1)&3) = (l15>>1)&3
  const int rq8 = (quad ^ ((l15 >> 1) & 3)) * 8;

  float lsum0 = 0.f, lsum1 = 0.f;          // two chains: halves serial depth
  f32x4 oacc[4] = {};

  __syncthreads();                         // drain prologue stage

  for (int nt = 0; nt < blockNt; nt++) {
    const int cur = nt & 1;
    if (nt + 1 < blockNt) {                // prefetch next tile into other buf
      const int n1 = (nt + 1) * 64;
      gl_lds16(Kg + (size_t)(n1 + k_s) * 512 + k_kc * 32 + chunk, &Ks[cur ^ 1][ldsW]);
      gl_lds16(Vg + (size_t)v_d * 4096 + n1 + v_sc * 32 + chunk, &Vs[cur ^ 1][ldsW]);
    }
    if (nt <= myLast) {
      const int n0 = nt * 64;
      const ushort* Kc = Ks[cur];
      const ushort* Vc = Vs[cur];
      // swapped QK^T: C[s][q], lane: q = l15, s = n0 + ct*16 + quad*4 + r
      f32x4 sc[4];
      __builtin_amdgcn_s_setprio(1);
#pragma unroll
      for (int ct = 0; ct < 4; ct++) {
        bf16x8 kf0 = *(const bf16x8*)&Kc[(ct * 16 + l15) * 32 + rq8];
        bf16x8 kf1 = *(const bf16x8*)&Kc[2048 + (ct * 16 + l15) * 32 + rq8];
        f32x4 z = {0.f, 0.f, 0.f, 0.f};
        z = __builtin_amdgcn_mfma_f32_16x16x32_bf16(kf0, qf[0], z, 0, 0, 0);
        z = __builtin_amdgcn_mfma_f32_16x16x32_bf16(kf1, qf[1], z, 0, 0, 0);
        sc[ct] = z;
      }
      __builtin_amdgcn_s_setprio(0);
      if (nt == myLast) {                  // causal mask: s > q -> -inf
        const int qrow = wrow0 + l15;
#pragma unroll
        for (int ct = 0; ct < 4; ct++)
#pragma unroll
          for (int r = 0; r < 4; r++)
            if (n0 + ct * 16 + quad * 4 + r > qrow) sc[ct][r] = -INFINITY;
      }
#pragma unroll
      for (int ct = 0; ct < 4; ct++)
#pragma unroll
        for (int k = 0; k < 2; k++) {
          float pv0 = EXP2F(sc[ct][2 * k]     - 23.083120654223f);
          float pv1 = EXP2F(sc[ct][2 * k + 1] - 23.083120654223f);
          lsum0 += pv0;
          lsum1 += pv1;
          __hip_bfloat162 pk = __float22bfloat162_rn(make_float2(pv0, pv1));
          *(__hip_bfloat162*)&Ps[(wave * 16 + l15) * 72 + ct * 16 + quad * 4 + 2 * k] = pk;
        }
      // wave-private P rows: compiler inserts lgkmcnt for same-wave RAW
      bf16x8 pf0 = *(const bf16x8*)&Ps[(wave * 16 + l15) * 72 + quad * 8];
      bf16x8 pf1 = *(const bf16x8*)&Ps[(wave * 16 + l15) * 72 + 32 + quad * 8];
      __builtin_amdgcn_s_setprio(1);
#pragma unroll
      for (int dt = 0; dt < 4; dt++) {
        bf16x8 vf0 = *(const bf16x8*)&Vc[(dt * 16 + l15) * 32 + rq8];
        bf16x8 vf1 = *(const bf16x8*)&Vc[2048 + (dt * 16 + l15) * 32 + rq8];
        oacc[dt] = __builtin_amdgcn_mfma_f32_16x16x32_bf16(pf0, vf0, oacc[dt], 0, 0, 0);
        oacc[dt] = __builtin_amdgcn_mfma_f32_16x16x32_bf16(pf1, vf1, oacc[dt], 0, 0, 0);
      }
      __builtin_amdgcn_s_setprio(0);
    }
    __syncthreads();                       // one barrier/iter: drains prefetch
  }
  // combine chains; l for q = wrow0 + l15 (this lane's quad's s-slice)
  float l_loc = lsum0 + lsum1;
  l_loc += __shfl_xor(l_loc, 16, 64);
  l_loc += __shfl_xor(l_loc, 32, 64);      // now full sum, uniform across quads
  float linv[4];
#pragma unroll
  for (int r = 0; r < 4; r++) linv[r] = 1.f / __shfl(l_loc, quad * 4 + r, 64);
#pragma unroll
  for (int dt = 0; dt < 4; dt++)
#pragma unroll
    for (int r = 0; r < 4; r++) {
      int s = wrow0 + quad * 4 + r;
      Ob[(brow + s) * 2048 + h * 64 + dt * 16 + l15] = f2bf(oacc[dt][r] * linv[r]);
    }
}

extern "C" void kernel_launch(void* const* d_in, const int* in_sizes, int n_in,
                              void* d_out, int out_size, void* d_ws, size_t ws_size,
                              hipStream_t stream) {
  char* wsb = (char*)d_ws;
  int* flag = (int*)wsb;
  ushort* base = (ushort*)(wsb + 256);
  ushort* xb   = base + XB;
  ushort* wqb  = base + WQB;
  ushort* wkb  = base + WKB;
  ushort* wvb  = base + WVB;
  ushort* wob  = base + WOB;
  ushort* cosb = base + COSB;
  ushort* sinb = base + SINB;
  ushort* qb   = base + QB;
  ushort* kb   = base + KB;
  ushort* vtb  = base + VTB;
  ushort* abuf = xb;   // attn output reuses x region

  const ushort* xo  = (const ushort*)d_in[0];
  const ushort* co  = (const ushort*)d_in[1];
  const ushort* so  = (const ushort*)d_in[2];
  const ushort* wqo = (const ushort*)d_in[4];
  const ushort* wko = (const ushort*)d_in[5];
  const ushort* wvo = (const ushort*)d_in[6];
  const ushort* woo = (const ushort*)d_in[7];

  cast_all<<<4096, 256, 0, stream>>>(d_in[0], d_in[4], d_in[5], d_in[6], d_in[7],
                                     d_in[1], d_in[2],
                                     xb, wqb, wkb, wvb, wob, cosb, sinb, flag);

  gemm_qkv<<<768, 256, 0, stream>>>(xb, xo, wqb, wqo, wkb, wko, wvb, wvo,
                                    qb, kb, vtb, flag);

  rope_kernel<<<512, 256, 0, stream>>>(kb, cosb, co, sinb, so, flag);

  attn_kernel<<<1024, 512, 0, stream>>>(qb, kb, vtb, cosb, co, sinb, so, abuf, flag);

  gemm_bt<<<dim3(16, 32), 256, 0, stream>>>(abuf, nullptr, wob, woo, d_out, 2048, 2048, flag, 1);
}

// Round 12
// 302.462 us; speedup vs baseline: 1.0133x; 1.0133x over previous
//
#include <hip/hip_runtime.h>
#include <hip/hip_bf16.h>
#include <math.h>

typedef __attribute__((ext_vector_type(8))) short bf16x8;
typedef __attribute__((ext_vector_type(4))) float f32x4;

__device__ __forceinline__ float bf2f(ushort u) {
  union { unsigned u; float f; } v; v.u = ((unsigned)u) << 16; return v.f;
}
__device__ __forceinline__ ushort f2bf(float f) {
  union { float f; unsigned u; } v; v.f = f;
  unsigned r = v.u + 0x7FFFu + ((v.u >> 16) & 1u);
  return (ushort)(r >> 16);
}
#if __has_builtin(__builtin_amdgcn_exp2f)
#define EXP2F(x) __builtin_amdgcn_exp2f(x)
#else
#define EXP2F(x) exp2f(x)
#endif
__device__ __forceinline__ void gl_lds16(const ushort* g, ushort* l) {
  __builtin_amdgcn_global_load_lds(
      (const __attribute__((address_space(1))) unsigned int*)g,
      (__attribute__((address_space(3))) unsigned int*)l, 16, 0, 0);
}

// -------- workspace layout (ushort elements, after 256B header) --------
static const long XB   = 0;              // x bf16 (4096x2048); reused as attn-out
static const long WQB  = 8388608;        // wq (2048x2048)
static const long WKB  = 12582912;       // wk (512x2048)
static const long WVB  = 13631488;       // wv (512x2048)
static const long WOB  = 14680064;       // wo (2048x2048)
static const long COSB = 18874368;       // cos (2*2048*64)
static const long SINB = 19136512;       // sin
static const long QB   = 19398656;       // q (4096x2048)
static const long KB   = 27787264;       // k (4096x512)
static const long VTB  = 29884416;       // v^T (512x4096)

// ---------------- fused cast of all 7 inputs + dtype self-detection --------
__global__ void cast_all(const void* __restrict__ s0, const void* __restrict__ s1,
                         const void* __restrict__ s2, const void* __restrict__ s3,
                         const void* __restrict__ s4, const void* __restrict__ s5,
                         const void* __restrict__ s6,
                         ushort* __restrict__ d0, ushort* __restrict__ d1,
                         ushort* __restrict__ d2, ushort* __restrict__ d3,
                         ushort* __restrict__ d4, ushort* __restrict__ d5,
                         ushort* __restrict__ d6, int* __restrict__ flag) {
  __shared__ int cnt;
  if (threadIdx.x == 0) cnt = 0;
  __syncthreads();
  const ushort* xu = (const ushort*)s0;
  int local = 0;
  for (int j = 0; j < 32; j++) {
    ushort u = xu[threadIdx.x + j * 256];
    int e = (u >> 7) & 0xFF;
    if (e >= 100 && e <= 142) local++;
  }
  atomicAdd(&cnt, local);
  __syncthreads();
  const bool isbf = (cnt >= 6554);
  if (threadIdx.x == 0 && blockIdx.x == 0) *flag = isbf ? 1 : 0;
  if (isbf) return;
  const long N = 2424832;
  for (long i = (long)blockIdx.x * blockDim.x + threadIdx.x; i < N;
       i += (long)gridDim.x * blockDim.x) {
    const float4* s; ushort* d; long off;
    if      (i < 1048576) { s = (const float4*)s0; d = d0; off = i; }
    else if (i < 1572864) { s = (const float4*)s1; d = d1; off = i - 1048576; }
    else if (i < 1703936) { s = (const float4*)s2; d = d2; off = i - 1572864; }
    else if (i < 1835008) { s = (const float4*)s3; d = d3; off = i - 1703936; }
    else if (i < 2359296) { s = (const float4*)s4; d = d4; off = i - 1835008; }
    else if (i < 2392064) { s = (const float4*)s5; d = d5; off = i - 2359296; }
    else                  { s = (const float4*)s6; d = d6; off = i - 2392064; }
    float4 a = s[2 * off], b = s[2 * off + 1];
    uint4 o;
    o.x = (unsigned)f2bf(a.x) | ((unsigned)f2bf(a.y) << 16);
    o.y = (unsigned)f2bf(a.z) | ((unsigned)f2bf(a.w) << 16);
    o.z = (unsigned)f2bf(b.x) | ((unsigned)f2bf(b.y) << 16);
    o.w = (unsigned)f2bf(b.z) | ((unsigned)f2bf(b.w) << 16);
    ((uint4*)d)[off] = o;
  }
}

// ---------------- bf16 GEMM body: C tile = A[M,K] * W[N,K]^T ----------------
// Round-3 verified structure (BK=32, 2 barriers/K-step, global_load_lds) —
// DO NOT PERTURB the schedule (R4/R5 ring-3, R6 dbuf, R8 BK=64 all regressed).
// R11: T2 chunk-swizzle (conflicts 6.29M -> 0; +2% — drain-masked per m252).
// R12: callers apply T1 XCD-aware block remap so panel-sharing blocks land on
// one XCD's L2 -> staging loads become L2-hits -> the per-K-step vmcnt drain
// (the m233 critical path) shortens.
__device__ __forceinline__ void gemm_body(
    const ushort* __restrict__ A, const ushort* __restrict__ W, void* __restrict__ C,
    int N, int K, int bm, int bn, bool ofp32, ushort* As, ushort* Ws) {
  const int tid = threadIdx.x;
  const int wave = tid >> 6, lane = tid & 63;
  const int quad = lane >> 4, l15 = lane & 15;
  const int wm = (wave >> 1) * 64, wn = (wave & 1) * 64;
  const int srow = tid >> 2;
  // swizzled source chunk: LDS chunk (tid&3) of row srow receives global
  // chunk (tid&3) ^ ((srow>>1)&3); row srow+64 has the same XOR
  const int sk = (((tid & 3) ^ ((srow >> 1) & 3)) * 8);
  const ushort* Ap = A + (size_t)(bm + srow) * K + sk;
  const ushort* Wp = W + (size_t)(bn + srow) * K + sk;
  ushort* AsW = As + wave * 512;
  ushort* WsW = Ws + wave * 512;
  // read-side swizzle constant: row = wm/wn + t*16 + l15 -> XOR = (l15>>1)&3
  const int rq8 = (quad ^ ((l15 >> 1) & 3)) * 8;
  f32x4 acc[4][4] = {};
  for (int k0 = 0; k0 < K; k0 += 32) {
    __syncthreads();
    gl_lds16(Ap + k0, AsW);
    gl_lds16(Ap + (size_t)64 * K + k0, AsW + 2048);
    gl_lds16(Wp + k0, WsW);
    gl_lds16(Wp + (size_t)64 * K + k0, WsW + 2048);
    __syncthreads();
    bf16x8 af[4], wf[4];
#pragma unroll
    for (int t = 0; t < 4; t++)
      af[t] = *(const bf16x8*)&As[(wm + t * 16 + l15) * 32 + rq8];
#pragma unroll
    for (int t = 0; t < 4; t++)
      wf[t] = *(const bf16x8*)&Ws[(wn + t * 16 + l15) * 32 + rq8];
#pragma unroll
    for (int mt = 0; mt < 4; mt++)
#pragma unroll
      for (int nt = 0; nt < 4; nt++)
        acc[mt][nt] = __builtin_amdgcn_mfma_f32_16x16x32_bf16(af[mt], wf[nt], acc[mt][nt], 0, 0, 0);
  }
  if (!ofp32) {
    ushort* Cb = (ushort*)C;
#pragma unroll
    for (int mt = 0; mt < 4; mt++)
#pragma unroll
      for (int nt = 0; nt < 4; nt++)
#pragma unroll
        for (int r = 0; r < 4; r++) {
          int row = bm + wm + mt * 16 + quad * 4 + r;
          int col = bn + wn + nt * 16 + l15;
          Cb[(size_t)row * N + col] = f2bf(acc[mt][nt][r]);
        }
  } else {
    float* Cf = (float*)C;
#pragma unroll
    for (int mt = 0; mt < 4; mt++)
#pragma unroll
      for (int nt = 0; nt < 4; nt++)
#pragma unroll
        for (int r = 0; r < 4; r++) {
          int row = bm + wm + mt * 16 + quad * 4 + r;
          int col = bn + wn + nt * 16 + l15;
          Cf[(size_t)row * N + col] = acc[mt][nt][r];
        }
  }
}

// fused Q/K/V^T projection: 1D grid 768. [0,512) Q; [512,640) K; [640,768) V^T.
// T1 XCD remap (768 = 8 x 96, bijective): XCD k processes logical ids
// [96k, 96k+96) = 6 full M-rows of panel-sharing blocks -> A-panels (0.5 MB
// per M-row, shared by 16 N-tiles) become per-XCD L2 hits instead of 8x
// HBM re-fetches. FETCH was 73.8 MB vs ~33.6 ideal.
__global__ __launch_bounds__(256) void gemm_qkv(
    const ushort* __restrict__ xws, const ushort* __restrict__ xorig,
    const ushort* __restrict__ wqws, const ushort* __restrict__ wqorig,
    const ushort* __restrict__ wkws, const ushort* __restrict__ wkorig,
    const ushort* __restrict__ wvws, const ushort* __restrict__ wvorig,
    ushort* __restrict__ qout, ushort* __restrict__ kout, ushort* __restrict__ vtout,
    const int* __restrict__ flag) {
  __shared__ __align__(16) ushort As[128 * 32];
  __shared__ __align__(16) ushort Ws[128 * 32];
  const bool bf = (*flag != 0);
  const ushort* x = bf ? xorig : xws;
  const int bid = blockIdx.x;
  const int id = (bid & 7) * 96 + (bid >> 3);   // T1: XCD-contiguous chunks
  if (id < 512) {
    gemm_body(x, bf ? wqorig : wqws, qout, 2048, 2048, (id >> 4) * 128, (id & 15) * 128, false, As, Ws);
  } else if (id < 640) {
    int t = id - 512;
    gemm_body(x, bf ? wkorig : wkws, kout, 512, 2048, (t >> 2) * 128, (t & 3) * 128, false, As, Ws);
  } else {
    int t = id - 640;
    gemm_body(bf ? wvorig : wvws, x, vtout, 4096, 2048, (t & 3) * 128, (t >> 2) * 128, false, As, Ws);
  }
}

// 1D grid 512 (= 8 x 64, bijective T1 remap); decode M-tile/N-tile from
// logical id (x-major as the old dim3(16,32) layout).
__global__ __launch_bounds__(256) void gemm_bt(
    const ushort* __restrict__ Aws, const ushort* __restrict__ Aorig,
    const ushort* __restrict__ Wws, const ushort* __restrict__ Worig,
    void* __restrict__ C, int N, int K, const int* __restrict__ flag, int outMode) {
  __shared__ __align__(16) ushort As[128 * 32];
  __shared__ __align__(16) ushort Ws[128 * 32];
  const bool bf = (*flag != 0);
  const ushort* A = (bf && Aorig) ? Aorig : Aws;
  const ushort* W = (bf && Worig) ? Worig : Wws;
  bool ofp32 = (outMode == 1) && !bf;
  const int bid = blockIdx.x;
  const int id = (bid & 7) * 64 + (bid >> 3);   // T1: XCD-contiguous chunks
  const int by = id >> 4, bx = id & 15;
  gemm_body(A, W, C, N, K, by * 128, bx * 128, ofp32, As, Ws);
}

// ---------------- RoPE (K only; Q rope fused into attn prologue) -----------
__global__ void rope_kernel(ushort* __restrict__ Kb,
                            const ushort* __restrict__ cws, const ushort* __restrict__ corig,
                            const ushort* __restrict__ sws, const ushort* __restrict__ sorig,
                            const int* __restrict__ flag) {
  const ushort* cb = (*flag) ? corig : cws;
  const ushort* sb = (*flag) ? sorig : sws;
  int j = blockIdx.x * 256 + threadIdx.x;   // 0..131071
  long row = j >> 5; int rest = j & 31; int c8 = (rest & 3) * 8;
  ushort* base = Kb + row * 512 + (rest >> 2) * 64 + c8;
  uint4 lo4 = *(const uint4*)base;
  uint4 hi4 = *(const uint4*)(base + 32);
  uint4 cl4 = *(const uint4*)(cb + row * 64 + c8);
  uint4 ch4 = *(const uint4*)(cb + row * 64 + c8 + 32);
  uint4 sl4 = *(const uint4*)(sb + row * 64 + c8);
  uint4 sh4 = *(const uint4*)(sb + row * 64 + c8 + 32);
  const ushort* lo = (const ushort*)&lo4; const ushort* hi = (const ushort*)&hi4;
  const ushort* cl = (const ushort*)&cl4; const ushort* ch = (const ushort*)&ch4;
  const ushort* sl = (const ushort*)&sl4; const ushort* sh = (const ushort*)&sh4;
  uint4 olo, ohi;
  ushort* po = (ushort*)&olo; ushort* ph = (ushort*)&ohi;
#pragma unroll
  for (int k = 0; k < 8; k++) {
    float l = bf2f(lo[k]), h = bf2f(hi[k]);
    po[k] = f2bf(l * bf2f(cl[k]) - h * bf2f(sl[k]));
    ph[k] = f2bf(h * bf2f(ch[k]) + l * bf2f(sh[k]));
  }
  *(uint4*)base = olo;
  *(uint4*)(base + 32) = ohi;
}

// ---------------- causal GQA flash attention ----------------
// Round-10 winner: swapped QK^T, fused Q-RoPE, K/V dbuf prefetch, LPT,
// T2 chunk-swizzle on K/V LDS (conflicts 11.89M -> ~0), softmax diet.
__global__ __launch_bounds__(512, 4) void attn_kernel(
    const ushort* __restrict__ Qb, const ushort* __restrict__ Kb,
    const ushort* __restrict__ Vt,
    const ushort* __restrict__ cws, const ushort* __restrict__ corig,
    const ushort* __restrict__ sws, const ushort* __restrict__ sorig,
    ushort* __restrict__ Ob, const int* __restrict__ flag) {
  __shared__ __align__(16) ushort Ks[2][4096];  // [buf][kc][s][32], chunk-swizzled
  __shared__ __align__(16) ushort Vs[2][4096];  // [buf][sc][d][32], chunk-swizzled
  __shared__ __align__(16) ushort Ps[128 * 72]; // [q][s], wave-private rows
  const int tid = threadIdx.x;
  const int wave = tid >> 6, lane = tid & 63;
  const int quad = lane >> 4, l15 = lane & 15;
  const int id = blockIdx.x;
  const int kvh = id & 7;                  // XCD-pinned KV head
  const int b = (id >> 3) & 1;
  const int hsub = (id >> 4) & 3;
  const int h = kvh * 4 + hsub;
  const int t = 15 - (id >> 6);            // LPT: heavy tiles dispatch first
  const size_t brow = (size_t)b * 2048;
  const ushort* Kg = Kb + brow * 512 + (size_t)kvh * 64;
  const ushort* Vg = Vt + (size_t)(kvh * 64) * 4096 + brow;

  // staging decode: each of the 8 waves stages 1 of 8 1KB segments of K and V.
  const int prow = wave * 16 + (lane >> 2);       // panel-row
  const int chunk = (((lane & 3) ^ ((prow >> 1) & 3)) * 8);
  const int k_s = prow & 63, k_kc = prow >> 6;
  const int v_d = prow & 63, v_sc = prow >> 6;
  const int ldsW = wave * 512;

  const int q0 = t * 128;
  const int wrow0 = q0 + wave * 16;
  const int blockNt = 2 * t + 2;
  const int myLast = wrow0 >> 6;           // last KV tile this wave computes

  // prologue: stage tile 0 into buffer 0
  gl_lds16(Kg + (size_t)k_s * 512 + k_kc * 32 + chunk, &Ks[0][ldsW]);
  gl_lds16(Vg + (size_t)v_d * 4096 + v_sc * 32 + chunk, &Vs[0][ldsW]);

  // ---- Q load + in-register RoPE (+ attn scale in log2 units) ----
  const ushort* cb = (*flag) ? corig : cws;
  const ushort* sp = (*flag) ? sorig : sws;
  const size_t qrow_g = brow + wrow0 + l15;
  bf16x8 qlo = *(const bf16x8*)&Qb[qrow_g * 2048 + h * 64 + quad * 8];
  bf16x8 qhi = *(const bf16x8*)&Qb[qrow_g * 2048 + h * 64 + 32 + quad * 8];
  bf16x8 cl = *(const bf16x8*)&cb[qrow_g * 64 + quad * 8];
  bf16x8 ch = *(const bf16x8*)&cb[qrow_g * 64 + 32 + quad * 8];
  bf16x8 sl = *(const bf16x8*)&sp[qrow_g * 64 + quad * 8];
  bf16x8 sh = *(const bf16x8*)&sp[qrow_g * 64 + 32 + quad * 8];
  bf16x8 qf[2];
  const float scl = 0.18033688011112f;     // 0.125 * log2(e)
#pragma unroll
  for (int j = 0; j < 8; j++) {
    float l = bf2f((ushort)qlo[j]), hg = bf2f((ushort)qhi[j]);
    qf[0][j] = (short)f2bf((l * bf2f((ushort)cl[j]) - hg * bf2f((ushort)sl[j])) * scl);
    qf[1][j] = (short)f2bf((hg * bf2f((ushort)ch[j]) + l * bf2f((ushort)sh[j])) * scl);
  }

  // read-side swizzle constant: row = ct*16 + l15 -> ((row>>1)&3) = (l15>>1)&3
  const int rq8 = (quad ^ ((l15 >> 1) & 3)) * 8;

  float lsum0 = 0.f, lsum1 = 0.f;          // two chains: halves serial depth
  f32x4 oacc[4] = {};

  __syncthreads();                         // drain prologue stage

  for (int nt = 0; nt < blockNt; nt++) {
    const int cur = nt & 1;
    if (nt + 1 < blockNt) {                // prefetch next tile into other buf
      const int n1 = (nt + 1) * 64;
      gl_lds16(Kg + (size_t)(n1 + k_s) * 512 + k_kc * 32 + chunk, &Ks[cur ^ 1][ldsW]);
      gl_lds16(Vg + (size_t)v_d * 4096 + n1 + v_sc * 32 + chunk, &Vs[cur ^ 1][ldsW]);
    }
    if (nt <= myLast) {
      const int n0 = nt * 64;
      const ushort* Kc = Ks[cur];
      const ushort* Vc = Vs[cur];
      // swapped QK^T: C[s][q], lane: q = l15, s = n0 + ct*16 + quad*4 + r
      f32x4 sc[4];
      __builtin_amdgcn_s_setprio(1);
#pragma unroll
      for (int ct = 0; ct < 4; ct++) {
        bf16x8 kf0 = *(const bf16x8*)&Kc[(ct * 16 + l15) * 32 + rq8];
        bf16x8 kf1 = *(const bf16x8*)&Kc[2048 + (ct * 16 + l15) * 32 + rq8];
        f32x4 z = {0.f, 0.f, 0.f, 0.f};
        z = __builtin_amdgcn_mfma_f32_16x16x32_bf16(kf0, qf[0], z, 0, 0, 0);
        z = __builtin_amdgcn_mfma_f32_16x16x32_bf16(kf1, qf[1], z, 0, 0, 0);
        sc[ct] = z;
      }
      __builtin_amdgcn_s_setprio(0);
      if (nt == myLast) {                  // causal mask: s > q -> -inf
        const int qrow = wrow0 + l15;
#pragma unroll
        for (int ct = 0; ct < 4; ct++)
#pragma unroll
          for (int r = 0; r < 4; r++)
            if (n0 + ct * 16 + quad * 4 + r > qrow) sc[ct][r] = -INFINITY;
      }
#pragma unroll
      for (int ct = 0; ct < 4; ct++)
#pragma unroll
        for (int k = 0; k < 2; k++) {
          float pv0 = EXP2F(sc[ct][2 * k]     - 23.083120654223f);
          float pv1 = EXP2F(sc[ct][2 * k + 1] - 23.083120654223f);
          lsum0 += pv0;
          lsum1 += pv1;
          __hip_bfloat162 pk = __float22bfloat162_rn(make_float2(pv0, pv1));
          *(__hip_bfloat162*)&Ps[(wave * 16 + l15) * 72 + ct * 16 + quad * 4 + 2 * k] = pk;
        }
      // wave-private P rows: compiler inserts lgkmcnt for same-wave RAW
      bf16x8 pf0 = *(const bf16x8*)&Ps[(wave * 16 + l15) * 72 + quad * 8];
      bf16x8 pf1 = *(const bf16x8*)&Ps[(wave * 16 + l15) * 72 + 32 + quad * 8];
      __builtin_amdgcn_s_setprio(1);
#pragma unroll
      for (int dt = 0; dt < 4; dt++) {
        bf16x8 vf0 = *(const bf16x8*)&Vc[(dt * 16 + l15) * 32 + rq8];
        bf16x8 vf1 = *(const bf16x8*)&Vc[2048 + (dt * 16 + l15) * 32 + rq8];
        oacc[dt] = __builtin_amdgcn_mfma_f32_16x16x32_bf16(pf0, vf0, oacc[dt], 0, 0, 0);
        oacc[dt] = __builtin_amdgcn_mfma_f32_16x16x32_bf16(pf1, vf1, oacc[dt], 0, 0, 0);
      }
      __builtin_amdgcn_s_setprio(0);
    }
    __syncthreads();                       // one barrier/iter: drains prefetch
  }
  // combine chains; l for q = wrow0 + l15 (this lane's quad's s-slice)
  float l_loc = lsum0 + lsum1;
  l_loc += __shfl_xor(l_loc, 16, 64);
  l_loc += __shfl_xor(l_loc, 32, 64);      // now full sum, uniform across quads
  float linv[4];
#pragma unroll
  for (int r = 0; r < 4; r++) linv[r] = 1.f / __shfl(l_loc, quad * 4 + r, 64);
#pragma unroll
  for (int dt = 0; dt < 4; dt++)
#pragma unroll
    for (int r = 0; r < 4; r++) {
      int s = wrow0 + quad * 4 + r;
      Ob[(brow + s) * 2048 + h * 64 + dt * 16 + l15] = f2bf(oacc[dt][r] * linv[r]);
    }
}

extern "C" void kernel_launch(void* const* d_in, const int* in_sizes, int n_in,
                              void* d_out, int out_size, void* d_ws, size_t ws_size,
                              hipStream_t stream) {
  char* wsb = (char*)d_ws;
  int* flag = (int*)wsb;
  ushort* base = (ushort*)(wsb + 256);
  ushort* xb   = base + XB;
  ushort* wqb  = base + WQB;
  ushort* wkb  = base + WKB;
  ushort* wvb  = base + WVB;
  ushort* wob  = base + WOB;
  ushort* cosb = base + COSB;
  ushort* sinb = base + SINB;
  ushort* qb   = base + QB;
  ushort* kb   = base + KB;
  ushort* vtb  = base + VTB;
  ushort* abuf = xb;   // attn output reuses x region

  const ushort* xo  = (const ushort*)d_in[0];
  const ushort* co  = (const ushort*)d_in[1];
  const ushort* so  = (const ushort*)d_in[2];
  const ushort* wqo = (const ushort*)d_in[4];
  const ushort* wko = (const ushort*)d_in[5];
  const ushort* wvo = (const ushort*)d_in[6];
  const ushort* woo = (const ushort*)d_in[7];

  cast_all<<<4096, 256, 0, stream>>>(d_in[0], d_in[4], d_in[5], d_in[6], d_in[7],
                                     d_in[1], d_in[2],
                                     xb, wqb, wkb, wvb, wob, cosb, sinb, flag);

  gemm_qkv<<<768, 256, 0, stream>>>(xb, xo, wqb, wqo, wkb, wko, wvb, wvo,
                                    qb, kb, vtb, flag);

  rope_kernel<<<512, 256, 0, stream>>>(kb, cosb, co, sinb, so, flag);

  attn_kernel<<<1024, 512, 0, stream>>>(qb, kb, vtb, cosb, co, sinb, so, abuf, flag);

  gemm_bt<<<512, 256, 0, stream>>>(abuf, nullptr, wob, woo, d_out, 2048, 2048, flag, 1);
}